// Round 10
// baseline (78.528 us; speedup 1.0000x reference)
//
#include <hip/hip_runtime.h>

#define N_NODES 50000
#define N_EDGES 800000
#define SCAN_NB 49        // ceil(50000 / 1024) blocks, 1024 elements per block

#define NBUCKETS 391      // ceil(50000/128): bucket = dst >> 7 (128 nodes each)
#define BIN_EDGES 4096    // edges per bin block
#define BIN_NB 196        // ceil(800000/4096)
#define BUCKET_CAP 2560   // slots per bucket (mean 2048, sd ~45 -> 11 sigma margin)

#define GEMM_NB ((N_NODES + 63) / 64)          // 782 gemm tiles (64 rows each)
#define FUSED_NB 980                           // 196*5; bid%5==4 -> bin role

typedef __attribute__((ext_vector_type(4))) _Float16 half4;
typedef __attribute__((ext_vector_type(8))) _Float16 half8;
typedef __attribute__((ext_vector_type(4))) float f32x4;

// Recover in-degree from GCN norm: norm = max(deg,1)^-0.5 (fp32).
// deg=0 reconstructs as 1 (harmless over-allocation; aggregate uses the
// post-scatter cursor as end pointer, so phantom slots are never read).
__device__ __forceinline__ int deg_from_norm(float n)
{
    return __float2int_rn(1.0f / (n * n));
}

// -------- Prep: Wt[c][k] = fp16(W[k][c]) ----------------------------------
// 32 KB fp16 transposed W; stays L2-hot, GEMM waves read B-fragments from it
// directly (no LDS staging).
__global__ __launch_bounds__(256) void prep_wt_kernel(
    const float* __restrict__ W, _Float16* __restrict__ Wt)
{
    const int e = blockIdx.x * 256 + threadIdx.x;   // 4096 threads
    const int c = e & 127;
    const int k4 = (e >> 7) << 2;
    half4 v;
    v.x = (_Float16)W[(k4 + 0) * 128 + c];
    v.y = (_Float16)W[(k4 + 1) * 128 + c];
    v.z = (_Float16)W[(k4 + 2) * 128 + c];
    v.w = (_Float16)W[(k4 + 3) * 128 + c];
    *(half4*)(Wt + (size_t)c * 128 + k4) = v;
}

// -------- Fused Kernel A: LDS-free MFMA gemm tiles + edge binning ---------
// Blocks with bid%5==4 bin 4096 edges into per-bucket sequential streams
// (bucket = dst>>7); the rest compute one 64-row GEMM tile (4 waves x 16
// rows) with mfma_f32_16x16x32_f16.
// Round-10 structure: the GEMM role has NO LDS and NO barriers — A-frags
// load straight from h (wave covers 16 rows x full 128B lines per k-step),
// B-frags load 16B each from the 32KB L2-hot Wt. MFMA made compute ~1us;
// what remained was the stage->barrier skeleton (52KB LDS, 3 blk/CU) —
// removed entirely. Occupancy is now VGPR-bound (~70 VGPR).
// Fragment layout (guide-verified 16x16x32): A/B lane l&15 = row/col,
// k = (l>>4)*8 + j; C/D col = l&15, row = (l>>4)*4 + reg.
// SESSION RULE (rounds 2 & 4): no min-waves clause — it collapses VGPRs and
// spills the accumulators (WRITE_SIZE tripwire 12.5 MB -> 183-564 MB).
__global__ __launch_bounds__(256) void fused_gemm_bin_kernel(
    const float* __restrict__ h, const float* __restrict__ norm,
    const _Float16* __restrict__ Wt, _Float16* __restrict__ t,
    const int* __restrict__ src, const int* __restrict__ dst,
    int* __restrict__ bcur, int2* __restrict__ bucketbuf)
{
    const int tid = threadIdx.x;
    const int bid = blockIdx.x;

    if (bid % 5 == 4) {
        // ---- bin role: 4096 edges -> 391 bucket streams --------------------
        __shared__ int hist[NBUCKETS];
        const int bs = (bid / 5) * BIN_EDGES;
        for (int i = tid; i < NBUCKETS; i += 256) hist[i] = 0;
        __syncthreads();
#pragma unroll
        for (int j = 0; j < 4; ++j) {
            int e4 = bs + (j * 256 + tid) * 4;
            if (e4 < N_EDGES) {               // 4096 & 1280 both %4==0
                int4 d4 = *(const int4*)(dst + e4);
                atomicAdd(&hist[d4.x >> 7], 1);
                atomicAdd(&hist[d4.y >> 7], 1);
                atomicAdd(&hist[d4.z >> 7], 1);
                atomicAdd(&hist[d4.w >> 7], 1);
            }
        }
        __syncthreads();
        for (int i = tid; i < NBUCKETS; i += 256) {
            int hc = hist[i];
            hist[i] = hc ? atomicAdd(&bcur[i], hc) : 0;
        }
        __syncthreads();
#pragma unroll
        for (int j = 0; j < 4; ++j) {
            int e4 = bs + (j * 256 + tid) * 4;
            if (e4 < N_EDGES) {
                int4 d4 = *(const int4*)(dst + e4);
                int4 s4 = *(const int4*)(src + e4);
                int b0, p;
                b0 = d4.x >> 7; p = atomicAdd(&hist[b0], 1);
                bucketbuf[(size_t)b0 * BUCKET_CAP + p] = make_int2(s4.x, d4.x);
                b0 = d4.y >> 7; p = atomicAdd(&hist[b0], 1);
                bucketbuf[(size_t)b0 * BUCKET_CAP + p] = make_int2(s4.y, d4.y);
                b0 = d4.z >> 7; p = atomicAdd(&hist[b0], 1);
                bucketbuf[(size_t)b0 * BUCKET_CAP + p] = make_int2(s4.z, d4.z);
                b0 = d4.w >> 7; p = atomicAdd(&hist[b0], 1);
                bucketbuf[(size_t)b0 * BUCKET_CAP + p] = make_int2(s4.w, d4.w);
            }
        }
        return;
    }

    // ---- gemm role: one 64-row tile, 4 waves x 16 rows, LDS-free MFMA ------
    const int gemm_id = bid - bid / 5;
    if (gemm_id >= GEMM_NB) return;
    const int rbase = gemm_id * 64;

    const int wid = tid >> 6, lane = tid & 63;
    const int lrow = lane & 15;            // A row / B col within 16-tile
    const int khi = (lane >> 4) << 3;      // k octet (in halves)
    const int r0 = wid * 16;
    const int gr = rbase + r0 + lrow;      // this lane's A row

    // A fragments straight from h (fp32 -> fp16), 8 float4 loads in flight
    half8 a[4];
#pragma unroll
    for (int ks = 0; ks < 4; ++ks) {
        float4 f0 = make_float4(0.f, 0.f, 0.f, 0.f);
        float4 f1 = f0;
        if (gr < N_NODES) {
            const float* hp = h + (size_t)gr * 128 + ks * 32 + khi;
            f0 = *(const float4*)hp;
            f1 = *(const float4*)(hp + 4);
        }
        half8 av;
        av[0] = (_Float16)f0.x; av[1] = (_Float16)f0.y;
        av[2] = (_Float16)f0.z; av[3] = (_Float16)f0.w;
        av[4] = (_Float16)f1.x; av[5] = (_Float16)f1.y;
        av[6] = (_Float16)f1.z; av[7] = (_Float16)f1.w;
        a[ks] = av;
    }

    // per-lane output rows (fixed across col-tiles) + their norms (L2-hot)
    const int rq = rbase + r0 + ((lane >> 4) << 2);
    float nv[4];
#pragma unroll
    for (int reg = 0; reg < 4; ++reg)
        nv[reg] = (rq + reg < N_NODES) ? norm[rq + reg] : 0.f;

#pragma unroll
    for (int ct = 0; ct < 8; ++ct) {
        const int c0 = ct * 16;
        f32x4 acc = {0.f, 0.f, 0.f, 0.f};
#pragma unroll
        for (int ks = 0; ks < 4; ++ks) {
            half8 bf = *(const half8*)(Wt + (size_t)(c0 + lrow) * 128 + ks * 32 + khi);
            acc = __builtin_amdgcn_mfma_f32_16x16x32_f16(a[ks], bf, acc, 0, 0, 0);
        }
#pragma unroll
        for (int reg = 0; reg < 4; ++reg) {
            if (rq + reg < N_NODES)
                t[(size_t)(rq + reg) * 128 + c0 + lrow] = (_Float16)(acc[reg] * nv[reg]);
        }
    }
}

// -------- CSR build step 1: per-block degree sums (from norm) -------------
// Block 0 also zeroes the 391 bucket cursors for the binning pass.
__global__ __launch_bounds__(256) void scan_sums_kernel(
    const float* __restrict__ norm, int* __restrict__ bsum,
    int* __restrict__ bcur)
{
    const int tid = threadIdx.x;
    if (blockIdx.x == 0) {
        for (int i = tid; i < NBUCKETS; i += 256) bcur[i] = 0;
    }
    const int idx = blockIdx.x * 1024 + tid * 4;
    int s = 0;
    if (idx < N_NODES) {                 // 50000 % 4 == 0: group fully in-range
        float4 n = *(const float4*)(norm + idx);
        s = deg_from_norm(n.x) + deg_from_norm(n.y) +
            deg_from_norm(n.z) + deg_from_norm(n.w);
    }
#pragma unroll
    for (int d = 32; d > 0; d >>= 1) s += __shfl_down(s, d);
    __shared__ int ws[4];
    if ((tid & 63) == 0) ws[tid >> 6] = s;
    __syncthreads();
    if (tid == 0) bsum[blockIdx.x] = ws[0] + ws[1] + ws[2] + ws[3];
}

// -------- CSR build step 2: exclusive scan of 49 block sums (1 wave) ------
__global__ __launch_bounds__(64) void scan_bsum_kernel(
    const int* __restrict__ bsum, int* __restrict__ boff)
{
    const int tid = threadIdx.x;
    int v = (tid < SCAN_NB) ? bsum[tid] : 0;
    int inc = v;
#pragma unroll
    for (int d = 1; d < 64; d <<= 1) {
        int u = __shfl_up(inc, d);
        if (tid >= d) inc += u;
    }
    if (tid < SCAN_NB) boff[tid] = inc - v;   // exclusive prefix
}

// -------- CSR build step 3: block-local scan + write off ------------------
__global__ __launch_bounds__(256) void scan_write_kernel(
    const float* __restrict__ norm, const int* __restrict__ boff,
    int* __restrict__ off)
{
    const int tid = threadIdx.x;
    const int idx = blockIdx.x * 1024 + tid * 4;

    int4 v = make_int4(0, 0, 0, 0);
    if (idx < N_NODES) {
        float4 n = *(const float4*)(norm + idx);
        v.x = deg_from_norm(n.x); v.y = deg_from_norm(n.y);
        v.z = deg_from_norm(n.z); v.w = deg_from_norm(n.w);
    }
    const int s = v.x + v.y + v.z + v.w;

    const int lane = tid & 63, w = tid >> 6;
    int inc = s;
#pragma unroll
    for (int d = 1; d < 64; d <<= 1) {
        int u = __shfl_up(inc, d);
        if (lane >= d) inc += u;
    }
    __shared__ int wsum[4];
    if (lane == 63) wsum[w] = inc;
    __syncthreads();
    int woff = 0;
    for (int i = 0; i < w; ++i) woff += wsum[i];

    int o0 = boff[blockIdx.x] + woff + inc - s;
    int o1 = o0 + v.x;
    int o2 = o1 + v.y;
    int o3 = o2 + v.z;

    if (idx < N_NODES) {
        *(int4*)(off + idx) = make_int4(o0, o1, o2, o3);
    }
}

// -------- Pass 2: bucket -> esrc scatter, LDS cursors ---------------------
// One block per bucket (128 dst nodes). Cursors live in LDS (no global
// atomics); the esrc write window per block is the bucket's contiguous
// ~8 KB segment -> L2-resident, lines fully filled before writeback.
// Final cursors -> cur (aggregate's end pointers; deg-0 phantom guard).
__global__ __launch_bounds__(256) void scatter_kernel(
    const int2* __restrict__ bucketbuf, const int* __restrict__ bcur,
    const int* __restrict__ off, int* __restrict__ cur,
    int* __restrict__ esrc)
{
    const int tid = threadIdx.x;
    const int b = blockIdx.x;
    __shared__ int lcur[128];
    const int g = b * 128 + tid;
    if (tid < 128) lcur[tid] = (g < N_NODES) ? off[g] : 0;
    __syncthreads();

    const int n = bcur[b];
    const int2* buf = bucketbuf + (size_t)b * BUCKET_CAP;
    for (int i = tid; i < n; i += 256) {
        int2 p = buf[i];
        int pos = atomicAdd(&lcur[p.y & 127], 1);
        esrc[pos] = p.x;
    }
    __syncthreads();
    if (tid < 128 && g < N_NODES) cur[g] = lcur[tid];
}

// -------- Kernel D: gather-aggregate (fp16 t) + fused finalize ------------
// 16 lanes per dst node; lane l owns halfs [8l..8l+7] (16 B load per edge).
// End pointer is cur[g] (post-scatter). Edge loop unrolled x2.
__global__ __launch_bounds__(256) void aggregate_kernel(
    const int* __restrict__ off, const int* __restrict__ cur,
    const int* __restrict__ esrc, const _Float16* __restrict__ t,
    const float* __restrict__ norm, const float* __restrict__ b,
    float* __restrict__ out)
{
    const int g = blockIdx.x * 16 + (threadIdx.x >> 4);
    if (g >= N_NODES) return;
    const int l = threadIdx.x & 15;
    const int c = l << 3;
    const int i0 = off[g], i1 = cur[g];

    float acc0[8], acc1[8];
#pragma unroll
    for (int j = 0; j < 8; ++j) { acc0[j] = 0.f; acc1[j] = 0.f; }

    int i = i0;
    for (; i + 2 <= i1; i += 2) {
        int s0 = esrc[i];
        int s1 = esrc[i + 1];
        half8 v0 = *(const half8*)(t + (size_t)s0 * 128 + c);
        half8 v1 = *(const half8*)(t + (size_t)s1 * 128 + c);
#pragma unroll
        for (int j = 0; j < 8; ++j) { acc0[j] += (float)v0[j]; acc1[j] += (float)v1[j]; }
    }
    if (i < i1) {
        int s0 = esrc[i];
        half8 v0 = *(const half8*)(t + (size_t)s0 * 128 + c);
#pragma unroll
        for (int j = 0; j < 8; ++j) acc0[j] += (float)v0[j];
    }

    const float nv = norm[g];
    const float4 b0 = *(const float4*)(b + c);
    const float4 b1 = *(const float4*)(b + c + 4);
    float4 o0 = make_float4((acc0[0] + acc1[0]) * nv + b0.x,
                            (acc0[1] + acc1[1]) * nv + b0.y,
                            (acc0[2] + acc1[2]) * nv + b0.z,
                            (acc0[3] + acc1[3]) * nv + b0.w);
    float4 o1 = make_float4((acc0[4] + acc1[4]) * nv + b1.x,
                            (acc0[5] + acc1[5]) * nv + b1.y,
                            (acc0[6] + acc1[6]) * nv + b1.z,
                            (acc0[7] + acc1[7]) * nv + b1.w);
    *(float4*)(out + (size_t)g * 128 + c) = o0;
    *(float4*)(out + (size_t)g * 128 + c + 4) = o1;
}

static inline size_t align256(size_t x) { return (x + 255) & ~(size_t)255; }

extern "C" void kernel_launch(void* const* d_in, const int* in_sizes, int n_in,
                              void* d_out, int out_size, void* d_ws, size_t ws_size,
                              hipStream_t stream)
{
    const float* h    = (const float*)d_in[0];
    const float* norm = (const float*)d_in[1];
    const float* W    = (const float*)d_in[2];
    const float* b    = (const float*)d_in[3];
    const int*   src  = (const int*)d_in[4];
    const int*   dst  = (const int*)d_in[5];
    float* out = (float*)d_out;

    // workspace layout
    char* ws = (char*)d_ws;
    size_t o = 0;
    _Float16* t = (_Float16*)(ws + o);  o = align256(o + (size_t)N_NODES * 128 * 2);
    _Float16* Wt = (_Float16*)(ws + o); o = align256(o + (size_t)128 * 128 * 2);
    int* off = (int*)(ws + o);          o = align256(o + (size_t)N_NODES * 4);
    int* cur = (int*)(ws + o);          o = align256(o + (size_t)N_NODES * 4);
    int* esrc = (int*)(ws + o);         o = align256(o + ((size_t)N_EDGES + 1024) * 4);
    int* bsum = (int*)(ws + o);         o = align256(o + (size_t)SCAN_NB * 4);
    int* boff = (int*)(ws + o);         o = align256(o + (size_t)SCAN_NB * 4);
    int* bcur = (int*)(ws + o);         o = align256(o + (size_t)NBUCKETS * 4);
    int2* bucketbuf = (int2*)(ws + o);  o = align256(o + (size_t)NBUCKETS * BUCKET_CAP * 8);

    prep_wt_kernel<<<16, 256, 0, stream>>>(W, Wt);
    scan_sums_kernel<<<SCAN_NB, 256, 0, stream>>>(norm, bsum, bcur);
    scan_bsum_kernel<<<1, 64, 0, stream>>>(bsum, boff);
    scan_write_kernel<<<SCAN_NB, 256, 0, stream>>>(norm, boff, off);
    fused_gemm_bin_kernel<<<FUSED_NB, 256, 0, stream>>>(h, norm, Wt, t,
                                                        src, dst, bcur, bucketbuf);
    scatter_kernel<<<NBUCKETS, 256, 0, stream>>>(bucketbuf, bcur, off, cur, esrc);
    aggregate_kernel<<<(N_NODES + 15) / 16, 256, 0, stream>>>(off, cur, esrc, t, norm, b, out);
}

// Round 11
// 72.576 us; speedup vs baseline: 1.0820x; 1.0820x over previous
//
#include <hip/hip_runtime.h>

#define N_NODES 50000
#define N_EDGES 800000

#define NBUCKETS 391      // ceil(50000/128): bucket = dst >> 7 (128 nodes each)
#define BIN_EDGES 4096    // edges per bin block
#define BIN_NB 196        // ceil(800000/4096)
#define BUCKET_CAP 2560   // slots per bucket (mean 2048, sd ~45 -> 11 sigma)

#define GEMM_NB ((N_NODES + 63) / 64)          // 782 gemm tiles (64 rows each)
#define FUSED_NB 980                           // 196*5; bid%5==4 -> bin role

typedef __attribute__((ext_vector_type(4))) _Float16 half4;
typedef __attribute__((ext_vector_type(8))) _Float16 half8;
typedef __attribute__((ext_vector_type(4))) float f32x4;

// -------- Prep: Wt[c][k] = fp16(W[k][c]) ----------------------------------
// 32 KB fp16 transposed W; L2-hot source for the GEMM role's LDS stage.
__global__ __launch_bounds__(256) void prep_wt_kernel(
    const float* __restrict__ W, _Float16* __restrict__ Wt)
{
    const int e = blockIdx.x * 256 + threadIdx.x;   // 4096 threads
    const int c = e & 127;
    const int k4 = (e >> 7) << 2;
    half4 v;
    v.x = (_Float16)W[(k4 + 0) * 128 + c];
    v.y = (_Float16)W[(k4 + 1) * 128 + c];
    v.z = (_Float16)W[(k4 + 2) * 128 + c];
    v.w = (_Float16)W[(k4 + 3) * 128 + c];
    *(half4*)(Wt + (size_t)c * 128 + k4) = v;
}

// -------- Fused Kernel A: MFMA gemm tiles + edge binning ------------------
// Blocks with bid%5==4 bin 4096 edges into per-bucket streams of PACKED
// ints (src | (dst&127)<<16; src<65536) — halves bucketbuf traffic vs int2.
// Other blocks: one 64-row GEMM tile (4 waves x 16 rows),
// mfma_f32_16x16x32_f16. Wt staged once into LDS (pad 136 halves: lanes
// hit 8 banks 2-way on ds_read_b128 -> conflict-free per m136); A-frags
// straight from h (wave covers 16 rows x full 128B lines).
// Fragment layout (guide-verified 16x16x32): A/B lane l&15 = row/col,
// k = (l>>4)*8 + j; C/D col = l&15, row = (l>>4)*4 + reg.
// SESSION RULE (rounds 2 & 4): no min-waves clause — it collapses VGPRs and
// spills the accumulators (WRITE_SIZE tripwire 12.5 MB -> 183-564 MB).
__global__ __launch_bounds__(256) void fused_gemm_bin_kernel(
    const float* __restrict__ h, const float* __restrict__ norm,
    const _Float16* __restrict__ Wt, _Float16* __restrict__ t,
    const int* __restrict__ src, const int* __restrict__ dst,
    int* __restrict__ bcur, int* __restrict__ bucketbuf)
{
    __shared__ int hist[NBUCKETS];                     // bin role, 1.6 KB
    __shared__ __align__(16) _Float16 WtS[128 * 136];  // gemm role, 34.8 KB
    const int tid = threadIdx.x;
    const int bid = blockIdx.x;

    if (bid % 5 == 4) {
        // ---- bin role: 4096 edges -> 391 bucket streams --------------------
        const int bs = (bid / 5) * BIN_EDGES;
        for (int i = tid; i < NBUCKETS; i += 256) hist[i] = 0;
        __syncthreads();
#pragma unroll
        for (int j = 0; j < 4; ++j) {
            int e4 = bs + (j * 256 + tid) * 4;
            if (e4 < N_EDGES) {               // 4096 & 1280 both %4==0
                int4 d4 = *(const int4*)(dst + e4);
                atomicAdd(&hist[d4.x >> 7], 1);
                atomicAdd(&hist[d4.y >> 7], 1);
                atomicAdd(&hist[d4.z >> 7], 1);
                atomicAdd(&hist[d4.w >> 7], 1);
            }
        }
        __syncthreads();
        for (int i = tid; i < NBUCKETS; i += 256) {
            int hc = hist[i];
            hist[i] = hc ? atomicAdd(&bcur[i], hc) : 0;
        }
        __syncthreads();
#pragma unroll
        for (int j = 0; j < 4; ++j) {
            int e4 = bs + (j * 256 + tid) * 4;
            if (e4 < N_EDGES) {
                int4 d4 = *(const int4*)(dst + e4);
                int4 s4 = *(const int4*)(src + e4);
                int b0, p;
                b0 = d4.x >> 7; p = atomicAdd(&hist[b0], 1);
                bucketbuf[(size_t)b0 * BUCKET_CAP + p] = s4.x | ((d4.x & 127) << 16);
                b0 = d4.y >> 7; p = atomicAdd(&hist[b0], 1);
                bucketbuf[(size_t)b0 * BUCKET_CAP + p] = s4.y | ((d4.y & 127) << 16);
                b0 = d4.z >> 7; p = atomicAdd(&hist[b0], 1);
                bucketbuf[(size_t)b0 * BUCKET_CAP + p] = s4.z | ((d4.z & 127) << 16);
                b0 = d4.w >> 7; p = atomicAdd(&hist[b0], 1);
                bucketbuf[(size_t)b0 * BUCKET_CAP + p] = s4.w | ((d4.w & 127) << 16);
            }
        }
        return;
    }

    // ---- gemm role: one 64-row tile, 4 waves x 16 rows ---------------------
    const int gemm_id = bid - bid / 5;
    if (gemm_id >= GEMM_NB) return;
    const int rbase = gemm_id * 64;

    // stage Wt into LDS once (8 x half8 per thread, coalesced), one barrier
#pragma unroll
    for (int i = 0; i < 8; ++i) {
        int f = i * 256 + tid;            // 0..2047
        int c = f >> 4;                   // 0..127
        int k8 = (f & 15) << 3;           // 0..120
        *(half8*)(WtS + c * 136 + k8) = *(const half8*)(Wt + (size_t)c * 128 + k8);
    }
    __syncthreads();

    const int wid = tid >> 6, lane = tid & 63;
    const int lrow = lane & 15;            // A row / B col within 16-tile
    const int khi = (lane >> 4) << 3;      // k octet (in halves)
    const int r0 = wid * 16;
    const int gr = rbase + r0 + lrow;      // this lane's A row

    // A fragments straight from h (fp32 -> fp16), 8 float4 loads in flight
    half8 a[4];
#pragma unroll
    for (int ks = 0; ks < 4; ++ks) {
        float4 f0 = make_float4(0.f, 0.f, 0.f, 0.f);
        float4 f1 = f0;
        if (gr < N_NODES) {
            const float* hp = h + (size_t)gr * 128 + ks * 32 + khi;
            f0 = *(const float4*)hp;
            f1 = *(const float4*)(hp + 4);
        }
        half8 av;
        av[0] = (_Float16)f0.x; av[1] = (_Float16)f0.y;
        av[2] = (_Float16)f0.z; av[3] = (_Float16)f0.w;
        av[4] = (_Float16)f1.x; av[5] = (_Float16)f1.y;
        av[6] = (_Float16)f1.z; av[7] = (_Float16)f1.w;
        a[ks] = av;
    }

    // per-lane output rows (fixed across col-tiles) + their norms (L2-hot)
    const int rq = rbase + r0 + ((lane >> 4) << 2);
    float nv[4];
#pragma unroll
    for (int reg = 0; reg < 4; ++reg)
        nv[reg] = (rq + reg < N_NODES) ? norm[rq + reg] : 0.f;

#pragma unroll
    for (int ct = 0; ct < 8; ++ct) {
        const int c0 = ct * 16;
        f32x4 acc = {0.f, 0.f, 0.f, 0.f};
#pragma unroll
        for (int ks = 0; ks < 4; ++ks) {
            half8 bf = *(const half8*)(WtS + (c0 + lrow) * 136 + ks * 32 + khi);
            acc = __builtin_amdgcn_mfma_f32_16x16x32_f16(a[ks], bf, acc, 0, 0, 0);
        }
#pragma unroll
        for (int reg = 0; reg < 4; ++reg) {
            if (rq + reg < N_NODES)
                t[(size_t)(rq + reg) * 128 + c0 + lrow] = (_Float16)(acc[reg] * nv[reg]);
        }
    }
}

// -------- Scatter: bucket -> esrc with LOCAL per-bucket CSR ---------------
// One block per bucket (128 dst nodes). Builds the bucket's degree histogram
// in LDS, scans it locally, writes esrc into the bucket's fixed region
// [b*BUCKET_CAP, ...), and emits off[g]/cur[g] itself — the global scan
// kernels (and the deg_from_norm reconstruction) are deleted entirely.
__global__ __launch_bounds__(256) void scatter_kernel(
    const int* __restrict__ bucketbuf, const int* __restrict__ bcur,
    int* __restrict__ off, int* __restrict__ cur, int* __restrict__ esrc)
{
    const int tid = threadIdx.x;
    const int b = blockIdx.x;
    __shared__ int hist[128];   // counts, then inclusive prefix
    __shared__ int lcur[128];
    if (tid < 128) hist[tid] = 0;
    __syncthreads();

    const int n = bcur[b];
    const int* buf = bucketbuf + (size_t)b * BUCKET_CAP;
    for (int i = tid; i < n; i += 256)
        atomicAdd(&hist[(buf[i] >> 16) & 127], 1);
    __syncthreads();

    const int cnt = (tid < 128) ? hist[tid] : 0;
    // inclusive Hillis-Steele over 128 entries (read, barrier, write, barrier)
    for (int d = 1; d < 128; d <<= 1) {
        int v = 0;
        if (tid < 128 && tid >= d) v = hist[tid - d];
        __syncthreads();
        if (tid < 128) hist[tid] += v;
        __syncthreads();
    }
    const int base = b * BUCKET_CAP;
    int o0 = 0;
    if (tid < 128) {
        o0 = base + hist[tid] - cnt;       // exclusive start within bucket
        lcur[tid] = o0;
    }
    __syncthreads();
    for (int i = tid; i < n; i += 256) {
        int p = buf[i];
        int pos = atomicAdd(&lcur[(p >> 16) & 127], 1);
        esrc[pos] = p & 0xFFFF;            // src index
    }
    __syncthreads();
    const int g = b * 128 + tid;
    if (tid < 128 && g < N_NODES) {
        off[g] = o0;
        cur[g] = lcur[tid];
    }
}

// -------- Kernel D: gather-aggregate (fp16 t) + fused finalize ------------
// 16 lanes per dst node; lane l owns halfs [8l..8l+7] (16 B load per edge).
// Edge loop unrolled x4: 4 independent gathers in flight per group raises
// memory-level parallelism (round-1 analysis: aggregate is outstanding-
// request-limited at ~3.2 TB/s, not traffic-limited).
__global__ __launch_bounds__(256) void aggregate_kernel(
    const int* __restrict__ off, const int* __restrict__ cur,
    const int* __restrict__ esrc, const _Float16* __restrict__ t,
    const float* __restrict__ norm, const float* __restrict__ b,
    float* __restrict__ out)
{
    const int g = blockIdx.x * 16 + (threadIdx.x >> 4);
    if (g >= N_NODES) return;
    const int l = threadIdx.x & 15;
    const int c = l << 3;
    const int i0 = off[g], i1 = cur[g];

    float acc0[8], acc1[8], acc2[8], acc3[8];
#pragma unroll
    for (int j = 0; j < 8; ++j) {
        acc0[j] = 0.f; acc1[j] = 0.f; acc2[j] = 0.f; acc3[j] = 0.f;
    }

    int i = i0;
    for (; i + 4 <= i1; i += 4) {
        int s0 = esrc[i], s1 = esrc[i + 1], s2 = esrc[i + 2], s3 = esrc[i + 3];
        half8 v0 = *(const half8*)(t + (size_t)s0 * 128 + c);
        half8 v1 = *(const half8*)(t + (size_t)s1 * 128 + c);
        half8 v2 = *(const half8*)(t + (size_t)s2 * 128 + c);
        half8 v3 = *(const half8*)(t + (size_t)s3 * 128 + c);
#pragma unroll
        for (int j = 0; j < 8; ++j) {
            acc0[j] += (float)v0[j]; acc1[j] += (float)v1[j];
            acc2[j] += (float)v2[j]; acc3[j] += (float)v3[j];
        }
    }
    for (; i < i1; ++i) {
        int s0 = esrc[i];
        half8 v0 = *(const half8*)(t + (size_t)s0 * 128 + c);
#pragma unroll
        for (int j = 0; j < 8; ++j) acc0[j] += (float)v0[j];
    }

    const float nv = norm[g];
    const float4 b0 = *(const float4*)(b + c);
    const float4 b1 = *(const float4*)(b + c + 4);
    float4 o0 = make_float4((acc0[0] + acc1[0] + acc2[0] + acc3[0]) * nv + b0.x,
                            (acc0[1] + acc1[1] + acc2[1] + acc3[1]) * nv + b0.y,
                            (acc0[2] + acc1[2] + acc2[2] + acc3[2]) * nv + b0.z,
                            (acc0[3] + acc1[3] + acc2[3] + acc3[3]) * nv + b0.w);
    float4 o1 = make_float4((acc0[4] + acc1[4] + acc2[4] + acc3[4]) * nv + b1.x,
                            (acc0[5] + acc1[5] + acc2[5] + acc3[5]) * nv + b1.y,
                            (acc0[6] + acc1[6] + acc2[6] + acc3[6]) * nv + b1.z,
                            (acc0[7] + acc1[7] + acc2[7] + acc3[7]) * nv + b1.w);
    *(float4*)(out + (size_t)g * 128 + c) = o0;
    *(float4*)(out + (size_t)g * 128 + c + 4) = o1;
}

static inline size_t align256(size_t x) { return (x + 255) & ~(size_t)255; }

extern "C" void kernel_launch(void* const* d_in, const int* in_sizes, int n_in,
                              void* d_out, int out_size, void* d_ws, size_t ws_size,
                              hipStream_t stream)
{
    const float* h    = (const float*)d_in[0];
    const float* norm = (const float*)d_in[1];
    const float* W    = (const float*)d_in[2];
    const float* b    = (const float*)d_in[3];
    const int*   src  = (const int*)d_in[4];
    const int*   dst  = (const int*)d_in[5];
    float* out = (float*)d_out;

    // workspace layout
    char* ws = (char*)d_ws;
    size_t o = 0;
    _Float16* t = (_Float16*)(ws + o);  o = align256(o + (size_t)N_NODES * 128 * 2);
    _Float16* Wt = (_Float16*)(ws + o); o = align256(o + (size_t)128 * 128 * 2);
    int* off = (int*)(ws + o);          o = align256(o + (size_t)N_NODES * 4);
    int* cur = (int*)(ws + o);          o = align256(o + (size_t)N_NODES * 4);
    int* esrc = (int*)(ws + o);         o = align256(o + (size_t)NBUCKETS * BUCKET_CAP * 4);
    int* bcur = (int*)(ws + o);         o = align256(o + (size_t)NBUCKETS * 4);
    int* bucketbuf = (int*)(ws + o);    o = align256(o + (size_t)NBUCKETS * BUCKET_CAP * 4);

    hipMemsetAsync(bcur, 0, (size_t)NBUCKETS * 4, stream);
    prep_wt_kernel<<<16, 256, 0, stream>>>(W, Wt);
    fused_gemm_bin_kernel<<<FUSED_NB, 256, 0, stream>>>(h, norm, Wt, t,
                                                        src, dst, bcur, bucketbuf);
    scatter_kernel<<<NBUCKETS, 256, 0, stream>>>(bucketbuf, bcur, off, cur, esrc);
    aggregate_kernel<<<(N_NODES + 15) / 16, 256, 0, stream>>>(off, cur, esrc, t, norm, b, out);
}

// Round 12
// 60.125 us; speedup vs baseline: 1.3061x; 1.2071x over previous
//
#include <hip/hip_runtime.h>

#define N_NODES 50000
#define N_EDGES 800000

#define NBUCKETS 782      // ceil(50000/64): bucket = dst >> 6 (64 nodes each)
#define BIN_EDGES 4096    // edges per bin block
#define BIN_NB 196        // ceil(800000/4096)
#define BUCKET_CAP 1280   // slots per bucket (mean ~1023, sd ~32 -> +8 sigma)

#define GEMM_NB ((N_NODES + 63) / 64)          // 782 gemm tiles (64 rows each)
#define FUSED_NB 980                           // 196*5; bid%5==4 -> bin role

typedef __attribute__((ext_vector_type(4))) _Float16 half4;
typedef __attribute__((ext_vector_type(8))) _Float16 half8;
typedef __attribute__((ext_vector_type(4))) float f32x4;

// -------- Prep: Wt[c][k] = fp16(W[k][c]); block 0 zeroes bcur -------------
// 32 KB fp16 transposed W; L2-hot source for the GEMM role's LDS stage.
__global__ __launch_bounds__(256) void prep_wt_kernel(
    const float* __restrict__ W, _Float16* __restrict__ Wt,
    int* __restrict__ bcur)
{
    const int tid = threadIdx.x;
    if (blockIdx.x == 0) {
        for (int i = tid; i < NBUCKETS; i += 256) bcur[i] = 0;
    }
    const int e = blockIdx.x * 256 + tid;           // 4096 threads
    const int c = e & 127;
    const int k4 = (e >> 7) << 2;
    half4 v;
    v.x = (_Float16)W[(k4 + 0) * 128 + c];
    v.y = (_Float16)W[(k4 + 1) * 128 + c];
    v.z = (_Float16)W[(k4 + 2) * 128 + c];
    v.w = (_Float16)W[(k4 + 3) * 128 + c];
    *(half4*)(Wt + (size_t)c * 128 + k4) = v;
}

// -------- Fused Kernel A: MFMA gemm tiles + edge binning ------------------
// Blocks with bid%5==4 bin 4096 edges into per-bucket streams of PACKED
// ints (src | (dst&63)<<16; src<65536). Other blocks: one 64-row GEMM tile
// (4 waves x 16 rows), mfma_f32_16x16x32_f16; Wt staged once into LDS
// (pad 136 halves -> conflict-free ds_read_b128), A-frags straight from h.
// Fragment layout (guide-verified 16x16x32): A/B lane l&15 = row/col,
// k = (l>>4)*8 + j; C/D col = l&15, row = (l>>4)*4 + reg.
// SESSION RULE (rounds 2 & 4): no min-waves clause — it collapses VGPRs and
// spills the accumulators (WRITE_SIZE tripwire 12.5 MB -> 183-564 MB).
__global__ __launch_bounds__(256) void fused_gemm_bin_kernel(
    const float* __restrict__ h, const float* __restrict__ norm,
    const _Float16* __restrict__ Wt, _Float16* __restrict__ t,
    const int* __restrict__ src, const int* __restrict__ dst,
    int* __restrict__ bcur, int* __restrict__ bucketbuf)
{
    __shared__ int hist[NBUCKETS];                     // bin role, 3.1 KB
    __shared__ __align__(16) _Float16 WtS[128 * 136];  // gemm role, 34.8 KB
    const int tid = threadIdx.x;
    const int bid = blockIdx.x;

    if (bid % 5 == 4) {
        // ---- bin role: 4096 edges -> 782 bucket streams --------------------
        const int bs = (bid / 5) * BIN_EDGES;
        for (int i = tid; i < NBUCKETS; i += 256) hist[i] = 0;
        __syncthreads();
#pragma unroll
        for (int j = 0; j < 4; ++j) {
            int e4 = bs + (j * 256 + tid) * 4;
            if (e4 < N_EDGES) {               // 4096 & 1280 both %4==0
                int4 d4 = *(const int4*)(dst + e4);
                atomicAdd(&hist[d4.x >> 6], 1);
                atomicAdd(&hist[d4.y >> 6], 1);
                atomicAdd(&hist[d4.z >> 6], 1);
                atomicAdd(&hist[d4.w >> 6], 1);
            }
        }
        __syncthreads();
        for (int i = tid; i < NBUCKETS; i += 256) {
            int hc = hist[i];
            hist[i] = hc ? atomicAdd(&bcur[i], hc) : 0;
        }
        __syncthreads();
#pragma unroll
        for (int j = 0; j < 4; ++j) {
            int e4 = bs + (j * 256 + tid) * 4;
            if (e4 < N_EDGES) {
                int4 d4 = *(const int4*)(dst + e4);
                int4 s4 = *(const int4*)(src + e4);
                int b0, p;
                b0 = d4.x >> 6; p = atomicAdd(&hist[b0], 1);
                bucketbuf[(size_t)b0 * BUCKET_CAP + p] = s4.x | ((d4.x & 63) << 16);
                b0 = d4.y >> 6; p = atomicAdd(&hist[b0], 1);
                bucketbuf[(size_t)b0 * BUCKET_CAP + p] = s4.y | ((d4.y & 63) << 16);
                b0 = d4.z >> 6; p = atomicAdd(&hist[b0], 1);
                bucketbuf[(size_t)b0 * BUCKET_CAP + p] = s4.z | ((d4.z & 63) << 16);
                b0 = d4.w >> 6; p = atomicAdd(&hist[b0], 1);
                bucketbuf[(size_t)b0 * BUCKET_CAP + p] = s4.w | ((d4.w & 63) << 16);
            }
        }
        return;
    }

    // ---- gemm role: one 64-row tile, 4 waves x 16 rows ---------------------
    const int gemm_id = bid - bid / 5;
    if (gemm_id >= GEMM_NB) return;
    const int rbase = gemm_id * 64;

    // stage Wt into LDS once (8 x half8 per thread, coalesced), one barrier
#pragma unroll
    for (int i = 0; i < 8; ++i) {
        int f = i * 256 + tid;            // 0..2047
        int c = f >> 4;                   // 0..127
        int k8 = (f & 15) << 3;           // 0..120
        *(half8*)(WtS + c * 136 + k8) = *(const half8*)(Wt + (size_t)c * 128 + k8);
    }
    __syncthreads();

    const int wid = tid >> 6, lane = tid & 63;
    const int lrow = lane & 15;            // A row / B col within 16-tile
    const int khi = (lane >> 4) << 3;      // k octet (in halves)
    const int r0 = wid * 16;
    const int gr = rbase + r0 + lrow;      // this lane's A row

    // A fragments straight from h (fp32 -> fp16), 8 float4 loads in flight
    half8 a[4];
#pragma unroll
    for (int ks = 0; ks < 4; ++ks) {
        float4 f0 = make_float4(0.f, 0.f, 0.f, 0.f);
        float4 f1 = f0;
        if (gr < N_NODES) {
            const float* hp = h + (size_t)gr * 128 + ks * 32 + khi;
            f0 = *(const float4*)hp;
            f1 = *(const float4*)(hp + 4);
        }
        half8 av;
        av[0] = (_Float16)f0.x; av[1] = (_Float16)f0.y;
        av[2] = (_Float16)f0.z; av[3] = (_Float16)f0.w;
        av[4] = (_Float16)f1.x; av[5] = (_Float16)f1.y;
        av[6] = (_Float16)f1.z; av[7] = (_Float16)f1.w;
        a[ks] = av;
    }

    // per-lane output rows (fixed across col-tiles) + their norms (L2-hot)
    const int rq = rbase + r0 + ((lane >> 4) << 2);
    float nv[4];
#pragma unroll
    for (int reg = 0; reg < 4; ++reg)
        nv[reg] = (rq + reg < N_NODES) ? norm[rq + reg] : 0.f;

#pragma unroll
    for (int ct = 0; ct < 8; ++ct) {
        const int c0 = ct * 16;
        f32x4 acc = {0.f, 0.f, 0.f, 0.f};
#pragma unroll
        for (int ks = 0; ks < 4; ++ks) {
            half8 bf = *(const half8*)(WtS + (c0 + lrow) * 136 + ks * 32 + khi);
            acc = __builtin_amdgcn_mfma_f32_16x16x32_f16(a[ks], bf, acc, 0, 0, 0);
        }
#pragma unroll
        for (int reg = 0; reg < 4; ++reg) {
            if (rq + reg < N_NODES)
                t[(size_t)(rq + reg) * 128 + c0 + lrow] = (_Float16)(acc[reg] * nv[reg]);
        }
    }
}

// -------- Fused scatter+aggregate: sort bucket in LDS, gather, finalize ---
// One block per 64-node bucket (782 blocks ~ 3/CU, 12 waves/CU). Phase 1:
// LDS histogram + 1-wave shfl scan. Phase 2: place sorted srcs into slist
// (5 KB LDS) — the sorted edge list NEVER goes to global (deletes esrc/off/
// cur traffic and the separate scatter kernel). Phase 3: 16 groups of 16
// lanes aggregate 4 nodes each (x4-unrolled gathers for MLP); deg-0 nodes
// naturally produce acc=0 -> out = b.
__global__ __launch_bounds__(256) void scatter_aggregate_kernel(
    const int* __restrict__ bucketbuf, const int* __restrict__ bcur,
    const _Float16* __restrict__ t, const float* __restrict__ norm,
    const float* __restrict__ bias, float* __restrict__ out)
{
    const int tid = threadIdx.x;
    const int b = blockIdx.x;
    __shared__ int cnt[64];     // per-node counts (kept)
    __shared__ int endp[64];    // inclusive scan (segment ends)
    __shared__ int lcur[64];    // running cursors (start -> end)
    __shared__ int slist[BUCKET_CAP];

    if (tid < 64) cnt[tid] = 0;
    __syncthreads();

    const int n = bcur[b];
    const int* buf = bucketbuf + (size_t)b * BUCKET_CAP;
    for (int i = tid; i < n; i += 256)
        atomicAdd(&cnt[(buf[i] >> 16) & 63], 1);
    __syncthreads();

    if (tid < 64) {             // single-wave inclusive scan over 64 counts
        int c = cnt[tid];
        int inc = c;
#pragma unroll
        for (int d = 1; d < 64; d <<= 1) {
            int u = __shfl_up(inc, d);
            if (tid >= d) inc += u;
        }
        endp[tid] = inc;
        lcur[tid] = inc - c;    // exclusive start
    }
    __syncthreads();

    for (int i = tid; i < n; i += 256) {
        int p = buf[i];
        int pos = atomicAdd(&lcur[(p >> 16) & 63], 1);
        slist[pos] = p & 0xFFFF;
    }
    __syncthreads();

    // ---- aggregate phase: group q handles nodes q, q+16, q+32, q+48 -------
    const int q = tid >> 4, l = tid & 15, c = l << 3;
    const float4 b0 = *(const float4*)(bias + c);
    const float4 b1 = *(const float4*)(bias + c + 4);

    for (int r = 0; r < 4; ++r) {
        const int nl = q + (r << 4);
        const int g = b * 64 + nl;
        if (g >= N_NODES) continue;
        const int i1 = endp[nl];
        const int i0 = i1 - cnt[nl];

        float acc0[8], acc1[8], acc2[8], acc3[8];
#pragma unroll
        for (int j = 0; j < 8; ++j) {
            acc0[j] = 0.f; acc1[j] = 0.f; acc2[j] = 0.f; acc3[j] = 0.f;
        }

        int i = i0;
        for (; i + 4 <= i1; i += 4) {
            int s0 = slist[i], s1 = slist[i + 1];
            int s2 = slist[i + 2], s3 = slist[i + 3];
            half8 v0 = *(const half8*)(t + (size_t)s0 * 128 + c);
            half8 v1 = *(const half8*)(t + (size_t)s1 * 128 + c);
            half8 v2 = *(const half8*)(t + (size_t)s2 * 128 + c);
            half8 v3 = *(const half8*)(t + (size_t)s3 * 128 + c);
#pragma unroll
            for (int j = 0; j < 8; ++j) {
                acc0[j] += (float)v0[j]; acc1[j] += (float)v1[j];
                acc2[j] += (float)v2[j]; acc3[j] += (float)v3[j];
            }
        }
        for (; i < i1; ++i) {
            int s0 = slist[i];
            half8 v0 = *(const half8*)(t + (size_t)s0 * 128 + c);
#pragma unroll
            for (int j = 0; j < 8; ++j) acc0[j] += (float)v0[j];
        }

        const float nv = norm[g];
        float4 o0 = make_float4((acc0[0] + acc1[0] + acc2[0] + acc3[0]) * nv + b0.x,
                                (acc0[1] + acc1[1] + acc2[1] + acc3[1]) * nv + b0.y,
                                (acc0[2] + acc1[2] + acc2[2] + acc3[2]) * nv + b0.z,
                                (acc0[3] + acc1[3] + acc2[3] + acc3[3]) * nv + b0.w);
        float4 o1 = make_float4((acc0[4] + acc1[4] + acc2[4] + acc3[4]) * nv + b1.x,
                                (acc0[5] + acc1[5] + acc2[5] + acc3[5]) * nv + b1.y,
                                (acc0[6] + acc1[6] + acc2[6] + acc3[6]) * nv + b1.z,
                                (acc0[7] + acc1[7] + acc2[7] + acc3[7]) * nv + b1.w);
        *(float4*)(out + (size_t)g * 128 + c) = o0;
        *(float4*)(out + (size_t)g * 128 + c + 4) = o1;
    }
}

static inline size_t align256(size_t x) { return (x + 255) & ~(size_t)255; }

extern "C" void kernel_launch(void* const* d_in, const int* in_sizes, int n_in,
                              void* d_out, int out_size, void* d_ws, size_t ws_size,
                              hipStream_t stream)
{
    const float* h    = (const float*)d_in[0];
    const float* norm = (const float*)d_in[1];
    const float* W    = (const float*)d_in[2];
    const float* b    = (const float*)d_in[3];
    const int*   src  = (const int*)d_in[4];
    const int*   dst  = (const int*)d_in[5];
    float* out = (float*)d_out;

    // workspace layout
    char* ws = (char*)d_ws;
    size_t o = 0;
    _Float16* t = (_Float16*)(ws + o);  o = align256(o + (size_t)N_NODES * 128 * 2);
    _Float16* Wt = (_Float16*)(ws + o); o = align256(o + (size_t)128 * 128 * 2);
    int* bcur = (int*)(ws + o);         o = align256(o + (size_t)NBUCKETS * 4);
    int* bucketbuf = (int*)(ws + o);    o = align256(o + (size_t)NBUCKETS * BUCKET_CAP * 4);

    prep_wt_kernel<<<16, 256, 0, stream>>>(W, Wt, bcur);
    fused_gemm_bin_kernel<<<FUSED_NB, 256, 0, stream>>>(h, norm, Wt, t,
                                                        src, dst, bcur, bucketbuf);
    scatter_aggregate_kernel<<<NBUCKETS, 256, 0, stream>>>(bucketbuf, bcur,
                                                           t, norm, b, out);
}